// Round 5
// baseline (186.454 us; speedup 1.0000x reference)
//
#include <hip/hip_runtime.h>
#include <hip/hip_fp16.h>
#include <math.h>

#define NATOMS 50000
#define NNEIGH 48
#define ZMAXV 87
#define NREFV 7
#define NFREQV 23
#define KCNV 7
#define XPAD 24          /* fp32 alpha table row pad */
#define XPADH 32         /* fp16 A-row pad: 32 halfs = 64 B */
#define APB 8            /* atoms per block */
#define TPB 192          /* threads per block; 2 pairs (same atom) per thread */
#define PPB (APB * NNEIGH) /* 384 pairs per block */

#define C2BOHR 1.8897261258369282f
#define C2EV 13.605693012183622f
#define K2C 1.33333333333333333f
#define K4C 4.10451f
#define K5C 19.08857f
#define K6INV (1.0f / 254.5553148552f)
#define KNC 7.5f
#define EXP_GA 20.085536923187668f /* e^3 */
#define QRT3 1.3160740129524924f   /* 3^(1/4); folded so r4r2 = s'_i * s'_j */

__device__ __forceinline__ float sp(float x) { return log1pf(expf(x)); }

// Abramowitz-Stegun 7.1.26: |err| <= 1.5e-7 absolute, monotone, saturates.
__device__ __forceinline__ float fast_erf(float x) {
    float ax = fabsf(x);
    float t = 1.0f / fmaf(0.3275911f, ax, 1.0f);
    float poly = t * fmaf(t, fmaf(t, fmaf(t, fmaf(t, 1.061405429f, -1.453152027f),
                                          1.421413741f), -0.284496736f), 0.254829592f);
    float y = 1.0f - poly * __expf(-ax * ax);
    return copysignf(y, x);
}

// ---------------------------------------------------------------------------
// k_setup: softplus scalars, reference alpha table [87][7][24], per-atom
// {rcov,en} float2, zero outputs 1,2
// ---------------------------------------------------------------------------
__global__ __launch_bounds__(256) void k_setup(
    const int* __restrict__ Z, const int* __restrict__ refsys,
    const float* __restrict__ zeff, const float* __restrict__ refh,
    const float* __restrict__ sscale, const float* __restrict__ secaiw,
    const float* __restrict__ gam, const float* __restrict__ ascale,
    const float* __restrict__ alphaiw, const float* __restrict__ hcount,
    const float* __restrict__ rcov, const float* __restrict__ en,
    const float* __restrict__ s6r, const float* __restrict__ s8r,
    const float* __restrict__ a1r, const float* __restrict__ a2r,
    const float* __restrict__ sqr,
    float* __restrict__ scal_out, float* __restrict__ alpha_out,
    float2* __restrict__ re2_out, float* __restrict__ zero_out)
{
    int e = blockIdx.x * 256 + threadIdx.x;
    if (e == 0) {
        scal_out[0] = sp(s6r[0]);
        scal_out[1] = sp(s8r[0]);
        scal_out[2] = sp(a1r[0]);
        scal_out[3] = sp(a2r[0]);
        scal_out[4] = sp(sqr[0]);   // scaleq, reused by k_atoms phase C
    }
    if (e < 2 * NATOMS) zero_out[e] = 0.0f; // outputs 1 and 2 (zeros)
    if (e < NATOMS) {
        int z = Z[e];
        re2_out[e] = make_float2(rcov[z], en[z]);
    }
    if (e < ZMAXV * NREFV * XPAD) {
        int x = e % XPAD;
        int za = e / XPAD; // z*NREF + a
        float v = 0.0f;
        if (x < NFREQV) {
            float scaleq = sp(sqr[0]);
            int rs = refsys[za];
            float iz = zeff[rs];
            float qmod = iz + refh[za] * scaleq;
            float zeta = (qmod > 1e-8f)
                ? __expf(3.0f * (1.0f - __expf(gam[rs] * 2.0f * (1.0f - iz / qmod))))
                : EXP_GA;
            float asec = sscale[rs] * secaiw[rs * NFREQV + x] * zeta;
            v = fmaxf(ascale[za] * (alphaiw[za * NFREQV + x] - hcount[za] * asec), 0.0f);
        }
        alpha_out[e] = v;
    }
}

// ---------------------------------------------------------------------------
// k_atoms: 8 atoms/block, 192 threads, 2 same-atom pairs/thread.
// covcn -> gweights -> zeta -> fp16 A-row [32 halfs]:
// x<23 = sqrt(cpw*3/pi)*sum_a zt*alpha ; x==23 = 3^(1/4)*sqrt_r4r2[Z] ; 0.
// Streams (idx_j, r_ij) use nontemporal loads to keep re2 L2-resident.
// ---------------------------------------------------------------------------
__global__ __launch_bounds__(TPB) void k_atoms(
    const int* __restrict__ Z, const int* __restrict__ idx_j,
    const float* __restrict__ r_ij, const float* __restrict__ qa,
    const float* __restrict__ scal, const float* __restrict__ zeff,
    const float* __restrict__ gam, const float2* __restrict__ re2,
    const float* __restrict__ nmask, const float* __restrict__ nweight,
    const float* __restrict__ cn, const float* __restrict__ fixg,
    const float* __restrict__ refq, const float* __restrict__ cpw,
    const float* __restrict__ alpha_tab, const float* __restrict__ sr4r2,
    __half2* __restrict__ A_out2)
{
    __shared__ float sh[TPB];
    __shared__ float covcn[APB];
    __shared__ float gwl[APB][NREFV];
    __shared__ float ztl[APB][NREFV];
    const int t = threadIdx.x;
    const int a0 = blockIdx.x * APB;
    const int al = t / 24;           // atom-local 0..7
    const int kk = t - al * 24;      // pair-slot 0..23 (handles kk and kk+24)

    // Phase A: per-pair CN contribution, 2 same-atom pairs per thread
    {
        int p0 = blockIdx.x * PPB + al * NNEIGH + kk;
        int p1 = p0 + 24;
        int j0 = __builtin_nontemporal_load(idx_j + p0);
        int j1 = __builtin_nontemporal_load(idx_j + p1);
        float rr0 = __builtin_nontemporal_load(r_ij + p0);
        float rr1 = __builtin_nontemporal_load(r_ij + p1);
        float2 rej0 = re2[j0];
        float2 rej1 = re2[j1];
        float2 rei = re2[a0 + al];

        float r0 = rr0 * C2BOHR;
        float rco0 = K2C * (rei.x + rej0.x);
        float d0 = fabsf(rei.y - rej0.y) + K5C;
        float den0 = K4C * __expf(-d0 * d0 * K6INV);
        float t0 = den0 * 0.5f * (1.0f + fast_erf(-KNC * (r0 - rco0) / rco0));

        float r1 = rr1 * C2BOHR;
        float rco1 = K2C * (rei.x + rej1.x);
        float d1 = fabsf(rei.y - rej1.y) + K5C;
        float den1 = K4C * __expf(-d1 * d1 * K6INV);
        float t1 = den1 * 0.5f * (1.0f + fast_erf(-KNC * (r1 - rco1) / rco1));

        sh[t] = t0 + t1;
    }
    __syncthreads();
    if (t < APB) {
        float s = 0.0f;
        for (int k = 0; k < 24; k++) s += sh[t * 24 + k];
        covcn[t] = s;
    }
    __syncthreads();

    // Phase B: raw gaussian weights per (atom, ref)
    if (t < APB * NREFV) {
        int a_l = t / NREFV, a = t % NREFV;
        int zl = Z[a0 + a_l];
        float cc = covcn[a_l];
        const float* mB = nmask + (zl * NREFV + a) * KCNV;
        const float* wB = nweight + (zl * NREFV + a) * KCNV;
        const float* cB = cn + (zl * NREFV + a) * KCNV;
        float g = 0.0f;
        for (int k = 0; k < KCNV; k++) {
            float dc = cc - cB[k];
            g += mB[k] * __expf(-6.0f * wB[k] * dc * dc);
        }
        gwl[a_l][a] = g;
    }
    __syncthreads();

    // Phase C: normalize, charge-scaling zeta, zt = zeta * gweight
    if (t < APB * NREFV) {
        int a_l = t / NREFV, a = t % NREFV;
        int zl = Z[a0 + a_l];
        float norm = 0.0f;
        for (int b = 0; b < NREFV; b++) norm += gwl[a_l][b];
        float w = (norm > 1e-8f) ? (gwl[a_l][a] / norm) : fixg[zl * NREFV + a];
        float scaleq = scal[4];
        float iz = zeff[zl];
        float qref = iz + refq[zl * NREFV + a] * scaleq;
        float qmod = iz + qa[a0 + a_l];
        float zeta = (qmod > 1e-8f)
            ? __expf(3.0f * (1.0f - __expf(gam[zl] * 2.0f * (1.0f - qref / qmod))))
            : EXP_GA;
        ztl[a_l][a] = zeta * w;
    }
    __syncthreads();

    // Phase D: fp16 A-row write via half2 (8 atoms x 16 half2 = 128 threads)
    if (t < APB * (XPADH / 2)) {
        int a_l = t >> 4, xh = t & 15;
        int x0 = 2 * xh, x1 = 2 * xh + 1;
        int zl = Z[a0 + a_l];
        float v0 = 0.0f, v1 = 0.0f;
        if (x0 < NFREQV) {
            float s = 0.0f;
            #pragma unroll
            for (int a = 0; a < NREFV; a++)
                s += ztl[a_l][a] * alpha_tab[(zl * NREFV + a) * XPAD + x0];
            v0 = s * sqrtf(cpw[x0] * 0.9549296585513721f);
        }
        if (x1 < NFREQV) {
            float s = 0.0f;
            #pragma unroll
            for (int a = 0; a < NREFV; a++)
                s += ztl[a_l][a] * alpha_tab[(zl * NREFV + a) * XPAD + x1];
            v1 = s * sqrtf(cpw[x1] * 0.9549296585513721f);
        } else if (x1 == NFREQV) {
            v1 = QRT3 * sr4r2[zl];
        }
        A_out2[(size_t)(a0 + a_l) * (XPADH / 2) + xh] = __floats2half2_rn(v0, v1);
    }
}

// ---------------------------------------------------------------------------
// k_pairs: 8 atoms/block, 192 threads, 2 same-atom pairs/thread.
// c6 = dot23(A_i, A_j) (fp16 rows, fp32 accumulate); rational damping;
// register-combined pair energies; halved LDS segmented sum -> eatom.
// Streams (idx_j, r_ij) nontemporal so the 3.2 MB A-table stays L2-resident.
// ---------------------------------------------------------------------------
__global__ __launch_bounds__(TPB) void k_pairs(
    const int* __restrict__ idx_j, const float* __restrict__ r_ij,
    const float* __restrict__ scal, const __half* __restrict__ Ah,
    float* __restrict__ eatom)
{
    __shared__ float sh[TPB];
    __shared__ float Ai[APB][NFREQV];
    __shared__ float Asi[APB];
    const int t = threadIdx.x;
    const int a0 = blockIdx.x * APB;
    const int al = t / 24;
    const int kk = t - al * 24;

    // stage this block's 8 A-rows: t -> (al = t/24, x = t%24), exactly 192
    {
        float v = __half2float(Ah[(size_t)(a0 + al) * XPADH + kk]);
        if (kk < NFREQV) Ai[al][kk] = v;
        else Asi[al] = v;               // kk == 23 carries 3^(1/4)*sqrt_r4r2
    }
    __syncthreads();

    const float s6 = scal[0], s8 = scal[1], a1 = scal[2], a2 = scal[3];

    int p0 = blockIdx.x * PPB + al * NNEIGH + kk;
    int p1 = p0 + 24;
    int j0 = __builtin_nontemporal_load(idx_j + p0);
    int j1 = __builtin_nontemporal_load(idx_j + p1);
    float rr0 = __builtin_nontemporal_load(r_ij + p0);
    float rr1 = __builtin_nontemporal_load(r_ij + p1);

    // issue both 64B row gathers up front (6 independent 16B loads)
    const float4* P0 = (const float4*)(Ah + (size_t)j0 * XPADH);
    const float4* P1 = (const float4*)(Ah + (size_t)j1 * XPADH);
    float4 u0 = P0[0], u1 = P0[1], u2 = P0[2];
    float4 w0 = P1[0], w1 = P1[1], w2 = P1[2];

    float c60 = 0.0f, c61 = 0.0f, sj0 = 0.0f, sj1 = 0.0f;
    {
        const __half2* a2p[3] = { (const __half2*)&u0, (const __half2*)&u1, (const __half2*)&u2 };
        const __half2* b2p[3] = { (const __half2*)&w0, (const __half2*)&w1, (const __half2*)&w2 };
        #pragma unroll
        for (int seg = 0; seg < 3; seg++) {
            #pragma unroll
            for (int k = 0; k < 4; k++) {
                int x = seg * 8 + 2 * k;
                float2 fa = __half22float2(a2p[seg][k]);
                float2 fb = __half22float2(b2p[seg][k]);
                if (x < NFREQV) { c60 += fa.x * Ai[al][x]; c61 += fb.x * Ai[al][x]; }
                if (x + 1 < NFREQV) { c60 += fa.y * Ai[al][x + 1]; c61 += fb.y * Ai[al][x + 1]; }
                else if (x + 1 == NFREQV) { sj0 = fa.y; sj1 = fb.y; }
            }
        }
    }

    float e0, e1;
    {
        float r = rr0 * C2BOHR;
        float r4r2 = Asi[al] * sj0;     // 3^(1/4) folded into both factors
        float r0v = a1 * r4r2 + a2;
        float r2 = r * r, r4 = r2 * r2, r6 = r4 * r2, r8 = r4 * r4;
        float p2 = r0v * r0v, p4 = p2 * p2, p6 = p4 * p2, p8 = p4 * p4;
        e0 = -c60 * (s6 / (r6 + p6) + s8 * r4r2 * r4r2 / (r8 + p8)) * C2EV;
    }
    {
        float r = rr1 * C2BOHR;
        float r4r2 = Asi[al] * sj1;
        float r0v = a1 * r4r2 + a2;
        float r2 = r * r, r4 = r2 * r2, r6 = r4 * r2, r8 = r4 * r4;
        float p2 = r0v * r0v, p4 = p2 * p2, p6 = p4 * p2, p8 = p4 * p4;
        e1 = -c61 * (s6 / (r6 + p6) + s8 * r4r2 * r4r2 / (r8 + p8)) * C2EV;
    }

    sh[t] = e0 + e1;
    __syncthreads();
    if (t < APB) {
        float s = 0.0f;
        for (int k = 0; k < 24; k++) s += sh[t * 24 + k];
        eatom[a0 + t] = s;
    }
}

// ---------------------------------------------------------------------------
extern "C" void kernel_launch(void* const* d_in, const int* in_sizes, int n_in,
                              void* d_out, int out_size, void* d_ws, size_t ws_size,
                              hipStream_t stream)
{
    const int*   Z       = (const int*)  d_in[0];
    /* d_in[1] = idx_i: known structure repeat(arange(N),48), unused */
    const int*   idx_j   = (const int*)  d_in[2];
    const float* r_ij    = (const float*)d_in[3];
    const float* qa      = (const float*)d_in[4];
    const float* s6r     = (const float*)d_in[5];
    const float* s8r     = (const float*)d_in[6];
    const float* a1r     = (const float*)d_in[7];
    const float* a2r     = (const float*)d_in[8];
    const float* sqraw   = (const float*)d_in[9];
    const int*   refsys  = (const int*)  d_in[10];
    const float* zeff    = (const float*)d_in[11];
    const float* refh    = (const float*)d_in[12];
    const float* sscale  = (const float*)d_in[13];
    const float* secaiw  = (const float*)d_in[14];
    const float* gam     = (const float*)d_in[15];
    const float* ascale  = (const float*)d_in[16];
    const float* alphaiw = (const float*)d_in[17];
    const float* hcount  = (const float*)d_in[18];
    const float* cpw     = (const float*)d_in[19];
    const float* rcov    = (const float*)d_in[20];
    const float* en      = (const float*)d_in[21];
    const float* nmask   = (const float*)d_in[22];
    const float* nweight = (const float*)d_in[23];
    const float* cn      = (const float*)d_in[24];
    const float* fixg    = (const float*)d_in[25];
    const float* refq    = (const float*)d_in[26];
    const float* sr4r2   = (const float*)d_in[27];

    // ws layout (byte offsets, Ah 128B-aligned so each 64B row = one line):
    //   scal : 0       (64 B)
    //   alpha: 64      (87*7*24*4 = 58464 B)  -> ends 58528
    //   re2  : 58528   (50000*8 = 400000 B)   -> ends 458528
    //   Ah   : 458752  (50000*64 = 3.2e6 B)   [458752 = 3584*128]
    char* wsb = (char*)d_ws;
    float*  scal  = (float*)(wsb);
    float*  alpha = (float*)(wsb + 64);
    float2* re2   = (float2*)(wsb + 58528);
    __half* Ah    = (__half*)(wsb + 458752);

    float* eatom = (float*)d_out;
    float* zeros = eatom + NATOMS;

    k_setup<<<391, 256, 0, stream>>>(Z, refsys, zeff, refh, sscale, secaiw, gam,
                                     ascale, alphaiw, hcount, rcov, en,
                                     s6r, s8r, a1r, a2r, sqraw,
                                     scal, alpha, re2, zeros);
    k_atoms<<<NATOMS / APB, TPB, 0, stream>>>(
        Z, idx_j, r_ij, qa, scal, zeff, gam, re2,
        nmask, nweight, cn, fixg, refq, cpw, alpha, sr4r2, (__half2*)Ah);
    k_pairs<<<NATOMS / APB, TPB, 0, stream>>>(
        idx_j, r_ij, scal, Ah, eatom);
}

// Round 9
// 174.012 us; speedup vs baseline: 1.0715x; 1.0715x over previous
//
#include <hip/hip_runtime.h>
#include <hip/hip_fp16.h>
#include <math.h>

#define NATOMS 50000
#define NNEIGH 48
#define ZMAXV 87
#define NREFV 7
#define NFREQV 23
#define KCNV 7
#define XPAD 24          /* fp32 alpha table row pad */
#define XPADH 32         /* fp16 A-row pad: 32 halfs = 64 B */
#define APB 8            /* k_atoms: atoms per block */
#define TPB 192          /* k_atoms threads; 2 same-atom pairs per thread */
#define PPB (APB * NNEIGH)
#define P_APB 4          /* k_pairs: atoms per block */
#define P_TPB 256        /* k_pairs threads: 64 quads x 3 pairs = 192 pairs */

#define C2BOHR 1.8897261258369282f
#define C2EV 13.605693012183622f
#define K2C 1.33333333333333333f
#define K4C 4.10451f
#define K5C 19.08857f
#define K6INV (1.0f / 254.5553148552f)
#define KNC 7.5f
#define EXP_GA 20.085536923187668f /* e^3 */
#define QRT3 1.3160740129524924f   /* 3^(1/4); folded so r4r2 = s'_i * s'_j */

__device__ __forceinline__ float sp(float x) { return log1pf(expf(x)); }

// Abramowitz-Stegun 7.1.26: |err| <= 1.5e-7 absolute, monotone, saturates.
__device__ __forceinline__ float fast_erf(float x) {
    float ax = fabsf(x);
    float t = 1.0f / fmaf(0.3275911f, ax, 1.0f);
    float poly = t * fmaf(t, fmaf(t, fmaf(t, fmaf(t, 1.061405429f, -1.453152027f),
                                          1.421413741f), -0.284496736f), 0.254829592f);
    float y = 1.0f - poly * __expf(-ax * ax);
    return copysignf(y, x);
}

// ---------------------------------------------------------------------------
// k_setup: softplus scalars, reference alpha table [87][7][24], per-atom
// {rcov,en} float2, zero outputs 1,2
// ---------------------------------------------------------------------------
__global__ __launch_bounds__(256) void k_setup(
    const int* __restrict__ Z, const int* __restrict__ refsys,
    const float* __restrict__ zeff, const float* __restrict__ refh,
    const float* __restrict__ sscale, const float* __restrict__ secaiw,
    const float* __restrict__ gam, const float* __restrict__ ascale,
    const float* __restrict__ alphaiw, const float* __restrict__ hcount,
    const float* __restrict__ rcov, const float* __restrict__ en,
    const float* __restrict__ s6r, const float* __restrict__ s8r,
    const float* __restrict__ a1r, const float* __restrict__ a2r,
    const float* __restrict__ sqr,
    float* __restrict__ scal_out, float* __restrict__ alpha_out,
    float2* __restrict__ re2_out, float* __restrict__ zero_out)
{
    int e = blockIdx.x * 256 + threadIdx.x;
    if (e == 0) {
        scal_out[0] = sp(s6r[0]);
        scal_out[1] = sp(s8r[0]);
        scal_out[2] = sp(a1r[0]);
        scal_out[3] = sp(a2r[0]);
        scal_out[4] = sp(sqr[0]);   // scaleq, reused by k_atoms phase C
    }
    if (e < 2 * NATOMS) zero_out[e] = 0.0f; // outputs 1 and 2 (zeros)
    if (e < NATOMS) {
        int z = Z[e];
        re2_out[e] = make_float2(rcov[z], en[z]);
    }
    if (e < ZMAXV * NREFV * XPAD) {
        int x = e % XPAD;
        int za = e / XPAD; // z*NREF + a
        float v = 0.0f;
        if (x < NFREQV) {
            float scaleq = sp(sqr[0]);
            int rs = refsys[za];
            float iz = zeff[rs];
            float qmod = iz + refh[za] * scaleq;
            float zeta = (qmod > 1e-8f)
                ? __expf(3.0f * (1.0f - __expf(gam[rs] * 2.0f * (1.0f - iz / qmod))))
                : EXP_GA;
            float asec = sscale[rs] * secaiw[rs * NFREQV + x] * zeta;
            v = fmaxf(ascale[za] * (alphaiw[za * NFREQV + x] - hcount[za] * asec), 0.0f);
        }
        alpha_out[e] = v;
    }
}

// ---------------------------------------------------------------------------
// k_atoms: 8 atoms/block, 192 threads, 2 same-atom pairs/thread.
// covcn -> gweights -> zeta -> fp16 A-row [32 halfs]:
// x<23 = sqrt(cpw*3/pi)*sum_a zt*alpha ; x==23 = 3^(1/4)*sqrt_r4r2[Z] ; 0.
// ---------------------------------------------------------------------------
__global__ __launch_bounds__(TPB) void k_atoms(
    const int* __restrict__ Z, const int* __restrict__ idx_j,
    const float* __restrict__ r_ij, const float* __restrict__ qa,
    const float* __restrict__ scal, const float* __restrict__ zeff,
    const float* __restrict__ gam, const float2* __restrict__ re2,
    const float* __restrict__ nmask, const float* __restrict__ nweight,
    const float* __restrict__ cn, const float* __restrict__ fixg,
    const float* __restrict__ refq, const float* __restrict__ cpw,
    const float* __restrict__ alpha_tab, const float* __restrict__ sr4r2,
    __half2* __restrict__ A_out2)
{
    __shared__ float sh[TPB];
    __shared__ float covcn[APB];
    __shared__ float gwl[APB][NREFV];
    __shared__ float ztl[APB][NREFV];
    const int t = threadIdx.x;
    const int a0 = blockIdx.x * APB;
    const int al = t / 24;           // atom-local 0..7
    const int kk = t - al * 24;      // pair-slot 0..23 (handles kk and kk+24)

    // Phase A: per-pair CN contribution, 2 same-atom pairs per thread
    {
        int p0 = blockIdx.x * PPB + al * NNEIGH + kk;
        int p1 = p0 + 24;
        int j0 = idx_j[p0];
        int j1 = idx_j[p1];
        float rr0 = r_ij[p0];
        float rr1 = r_ij[p1];
        float2 rej0 = re2[j0];
        float2 rej1 = re2[j1];
        float2 rei = re2[a0 + al];

        float r0 = rr0 * C2BOHR;
        float rco0 = K2C * (rei.x + rej0.x);
        float d0 = fabsf(rei.y - rej0.y) + K5C;
        float den0 = K4C * __expf(-d0 * d0 * K6INV);
        float t0 = den0 * 0.5f * (1.0f + fast_erf(-KNC * (r0 - rco0) / rco0));

        float r1 = rr1 * C2BOHR;
        float rco1 = K2C * (rei.x + rej1.x);
        float d1 = fabsf(rei.y - rej1.y) + K5C;
        float den1 = K4C * __expf(-d1 * d1 * K6INV);
        float t1 = den1 * 0.5f * (1.0f + fast_erf(-KNC * (r1 - rco1) / rco1));

        sh[t] = t0 + t1;
    }
    __syncthreads();
    if (t < APB) {
        float s = 0.0f;
        for (int k = 0; k < 24; k++) s += sh[t * 24 + k];
        covcn[t] = s;
    }
    __syncthreads();

    // Phase B: raw gaussian weights per (atom, ref)
    if (t < APB * NREFV) {
        int a_l = t / NREFV, a = t % NREFV;
        int zl = Z[a0 + a_l];
        float cc = covcn[a_l];
        const float* mB = nmask + (zl * NREFV + a) * KCNV;
        const float* wB = nweight + (zl * NREFV + a) * KCNV;
        const float* cB = cn + (zl * NREFV + a) * KCNV;
        float g = 0.0f;
        for (int k = 0; k < KCNV; k++) {
            float dc = cc - cB[k];
            g += mB[k] * __expf(-6.0f * wB[k] * dc * dc);
        }
        gwl[a_l][a] = g;
    }
    __syncthreads();

    // Phase C: normalize, charge-scaling zeta, zt = zeta * gweight
    if (t < APB * NREFV) {
        int a_l = t / NREFV, a = t % NREFV;
        int zl = Z[a0 + a_l];
        float norm = 0.0f;
        for (int b = 0; b < NREFV; b++) norm += gwl[a_l][b];
        float w = (norm > 1e-8f) ? (gwl[a_l][a] / norm) : fixg[zl * NREFV + a];
        float scaleq = scal[4];
        float iz = zeff[zl];
        float qref = iz + refq[zl * NREFV + a] * scaleq;
        float qmod = iz + qa[a0 + a_l];
        float zeta = (qmod > 1e-8f)
            ? __expf(3.0f * (1.0f - __expf(gam[zl] * 2.0f * (1.0f - qref / qmod))))
            : EXP_GA;
        ztl[a_l][a] = zeta * w;
    }
    __syncthreads();

    // Phase D: fp16 A-row write via half2 (8 atoms x 16 half2 = 128 threads)
    if (t < APB * (XPADH / 2)) {
        int a_l = t >> 4, xh = t & 15;
        int x0 = 2 * xh, x1 = 2 * xh + 1;
        int zl = Z[a0 + a_l];
        float v0 = 0.0f, v1 = 0.0f;
        if (x0 < NFREQV) {
            float s = 0.0f;
            #pragma unroll
            for (int a = 0; a < NREFV; a++)
                s += ztl[a_l][a] * alpha_tab[(zl * NREFV + a) * XPAD + x0];
            v0 = s * sqrtf(cpw[x0] * 0.9549296585513721f);
        }
        if (x1 < NFREQV) {
            float s = 0.0f;
            #pragma unroll
            for (int a = 0; a < NREFV; a++)
                s += ztl[a_l][a] * alpha_tab[(zl * NREFV + a) * XPAD + x1];
            v1 = s * sqrtf(cpw[x1] * 0.9549296585513721f);
        } else if (x1 == NFREQV) {
            v1 = QRT3 * sr4r2[zl];
        }
        A_out2[(size_t)(a0 + a_l) * (XPADH / 2) + xh] = __floats2half2_rn(v0, v1);
    }
}

// ---------------------------------------------------------------------------
// k_pairs: quad-cooperative gathers. 4 atoms/block, 256 threads = 64 quads,
// each quad handles 3 pairs; the 4 lanes of a quad fetch the 4x16B chunks of
// the SAME 64B A_j row (16 distinct lines per wave-instr instead of 64).
// Dot vs zero-padded LDS A_i, quad __shfl_xor reduce, damping, seg-sum.
// ---------------------------------------------------------------------------
__global__ __launch_bounds__(P_TPB) void k_pairs(
    const int* __restrict__ idx_j, const float* __restrict__ r_ij,
    const float* __restrict__ scal, const __half* __restrict__ Ah,
    float* __restrict__ eatom)
{
    __shared__ float sh[P_APB * NNEIGH];   // 192 pair energies
    __shared__ float AiP[P_APB][32];       // cols 23..31 zeroed (pad)
    __shared__ float Asi[P_APB];
    const int t = threadIdx.x;
    const int a0 = blockIdx.x * P_APB;

    if (t < P_APB * 32) {
        int al = t >> 5, x = t & 31;
        float v = __half2float(Ah[(size_t)(a0 + al) * XPADH + x]);
        AiP[al][x] = (x < NFREQV) ? v : 0.0f;
        if (x == NFREQV) Asi[al] = v;      // 3^(1/4)*sqrt_r4r2 of atom i
    }
    __syncthreads();

    const float s6 = scal[0], s8 = scal[1], a1 = scal[2], a2 = scal[3];
    const int q = t >> 2;                  // quad id 0..63
    const int l = t & 3;                   // lane in quad
    const int pb = blockIdx.x * (P_APB * NNEIGH);

    int pl[3]; int jj[3]; float rr[3]; float4 ch[3];
    #pragma unroll
    for (int s = 0; s < 3; s++) {
        pl[s] = q + 64 * s;
        int p = pb + pl[s];
        jj[s] = idx_j[p];
        rr[s] = r_ij[p];
    }
    #pragma unroll
    for (int s = 0; s < 3; s++)
        ch[s] = ((const float4*)(Ah + (size_t)jj[s] * XPADH))[l];

    #pragma unroll
    for (int s = 0; s < 3; s++) {
        int al = pl[s] / NNEIGH;
        const __half2* h2 = (const __half2*)&ch[s];
        float part = 0.0f, sjp = 0.0f;
        int xb = l * 8;
        #pragma unroll
        for (int k = 0; k < 4; k++) {
            float2 f = __half22float2(h2[k]);
            int x0 = xb + 2 * k, x1 = x0 + 1;
            part += f.x * AiP[al][x0];      // pad cols give 0 for x>=23
            part += f.y * AiP[al][x1];
            if (x1 == NFREQV) sjp = f.y;    // lane 2, k=3 carries s'_j
        }
        part += __shfl_xor(part, 1, 64);
        part += __shfl_xor(part, 2, 64);
        sjp  += __shfl_xor(sjp, 1, 64);
        sjp  += __shfl_xor(sjp, 2, 64);

        float r = rr[s] * C2BOHR;
        float r4r2 = Asi[al] * sjp;         // 3^(1/4) folded into both factors
        float r0v = a1 * r4r2 + a2;
        float r2 = r * r, r4 = r2 * r2, r6 = r4 * r2, r8 = r4 * r4;
        float p2 = r0v * r0v, p4 = p2 * p2, p6 = p4 * p2, p8 = p4 * p4;
        float e = -part * (s6 / (r6 + p6) + s8 * r4r2 * r4r2 / (r8 + p8)) * C2EV;
        if (l == 0) sh[pl[s]] = e;
    }
    __syncthreads();
    if (t < P_APB) {
        float ssum = 0.0f;
        for (int k = 0; k < NNEIGH; k++) ssum += sh[t * NNEIGH + k];
        eatom[a0 + t] = ssum;
    }
}

// ---------------------------------------------------------------------------
extern "C" void kernel_launch(void* const* d_in, const int* in_sizes, int n_in,
                              void* d_out, int out_size, void* d_ws, size_t ws_size,
                              hipStream_t stream)
{
    const int*   Z       = (const int*)  d_in[0];
    /* d_in[1] = idx_i: known structure repeat(arange(N),48), unused */
    const int*   idx_j   = (const int*)  d_in[2];
    const float* r_ij    = (const float*)d_in[3];
    const float* qa      = (const float*)d_in[4];
    const float* s6r     = (const float*)d_in[5];
    const float* s8r     = (const float*)d_in[6];
    const float* a1r     = (const float*)d_in[7];
    const float* a2r     = (const float*)d_in[8];
    const float* sqraw   = (const float*)d_in[9];
    const int*   refsys  = (const int*)  d_in[10];
    const float* zeff    = (const float*)d_in[11];
    const float* refh    = (const float*)d_in[12];
    const float* sscale  = (const float*)d_in[13];
    const float* secaiw  = (const float*)d_in[14];
    const float* gam     = (const float*)d_in[15];
    const float* ascale  = (const float*)d_in[16];
    const float* alphaiw = (const float*)d_in[17];
    const float* hcount  = (const float*)d_in[18];
    const float* cpw     = (const float*)d_in[19];
    const float* rcov    = (const float*)d_in[20];
    const float* en      = (const float*)d_in[21];
    const float* nmask   = (const float*)d_in[22];
    const float* nweight = (const float*)d_in[23];
    const float* cn      = (const float*)d_in[24];
    const float* fixg    = (const float*)d_in[25];
    const float* refq    = (const float*)d_in[26];
    const float* sr4r2   = (const float*)d_in[27];

    // ws layout (byte offsets, Ah 128B-aligned so each 64B row = one line):
    //   scal : 0       (64 B)
    //   alpha: 64      (87*7*24*4 = 58464 B)  -> ends 58528
    //   re2  : 58528   (50000*8 = 400000 B)   -> ends 458528
    //   Ah   : 458752  (50000*64 = 3.2e6 B)   [458752 = 3584*128]
    char* wsb = (char*)d_ws;
    float*  scal  = (float*)(wsb);
    float*  alpha = (float*)(wsb + 64);
    float2* re2   = (float2*)(wsb + 58528);
    __half* Ah    = (__half*)(wsb + 458752);

    float* eatom = (float*)d_out;
    float* zeros = eatom + NATOMS;

    k_setup<<<391, 256, 0, stream>>>(Z, refsys, zeff, refh, sscale, secaiw, gam,
                                     ascale, alphaiw, hcount, rcov, en,
                                     s6r, s8r, a1r, a2r, sqraw,
                                     scal, alpha, re2, zeros);
    k_atoms<<<NATOMS / APB, TPB, 0, stream>>>(
        Z, idx_j, r_ij, qa, scal, zeff, gam, re2,
        nmask, nweight, cn, fixg, refq, cpw, alpha, sr4r2, (__half2*)Ah);
    k_pairs<<<NATOMS / P_APB, P_TPB, 0, stream>>>(
        idx_j, r_ij, scal, Ah, eatom);
}